// Round 1
// baseline (5602.848 us; speedup 1.0000x reference)
//
#include <hip/hip_runtime.h>

// GCN 2-layer: N=200000 nodes, E=6400000 edges, 14 -> 16(relu) -> 2 channels.
// Strategy (round 1 baseline):
//   - degree via float atomics on dst, dinv = rsqrt(deg) (deg incl. +1 self loop)
//   - layer1: scatter dinv[src]*x[src] (14ch) into aggx[dst] with f32 atomics
//     (aggregation is linear in x, W1 applied AFTER aggregation -> no h1 materialization)
//   - node kernel: out1 = (dinv*aggx + dinv^2*x) @ W1 + b1; relu; h2b = relu @ W2;
//     d_out initialized with self-loop term h2b*dinv^2 + b2
//   - layer2: scatter h2b[src]*dinv[src]*dinv[dst] (2ch) into d_out with f32 atomics
// edge_index dtype sniffed at runtime (int64 per reference vs int32 per harness hint).

constexpr int NN = 200000;
constexpr int NE = 6400000;
constexpr int IC = 14;
constexpr int HC = 16;
constexpr int OC = 2;

__global__ void k_flag(const void* __restrict__ ei, int* __restrict__ flag) {
    if (blockIdx.x == 0 && threadIdx.x == 0) {
        const unsigned long long* p = (const unsigned long long*)ei;
        unsigned long long acc = 0ULL;
        for (int i = 0; i < 64; ++i) acc |= (p[i] >> 32);
        *flag = (acc == 0ULL) ? 1 : 0;  // 1 => int64 indices, 0 => int32
    }
}

__global__ void k_init(float* __restrict__ deg, float* __restrict__ aggx) {
    int i = blockIdx.x * blockDim.x + threadIdx.x;
    if (i < NN * IC) aggx[i] = 0.0f;
    if (i < NN) deg[i] = 1.0f;  // self-loop
}

__device__ __forceinline__ void edge_ld(const void* __restrict__ ei, int fl, int e,
                                        int& s, int& d) {
    if (fl) {
        const long long* p = (const long long*)ei;
        s = (int)p[e];
        d = (int)p[NE + e];
    } else {
        const int* p = (const int*)ei;
        s = p[e];
        d = p[NE + e];
    }
}

__global__ void k_degree(const void* __restrict__ ei, const int* __restrict__ flag,
                         float* __restrict__ deg) {
    int e = blockIdx.x * blockDim.x + threadIdx.x;
    if (e >= NE) return;
    int fl = *flag;
    int s, d;
    edge_ld(ei, fl, e, s, d);
    atomicAdd(&deg[d], 1.0f);
}

__global__ void k_dinv(float* __restrict__ deg) {
    int i = blockIdx.x * blockDim.x + threadIdx.x;
    if (i < NN) deg[i] = rsqrtf(deg[i]);
}

__global__ void k_scatter1(const void* __restrict__ ei, const int* __restrict__ flag,
                           const float* __restrict__ x, const float* __restrict__ dinv,
                           float* __restrict__ aggx) {
    int e = blockIdx.x * blockDim.x + threadIdx.x;
    if (e >= NE) return;
    int fl = *flag;
    int s, d;
    edge_ld(ei, fl, e, s, d);
    float w = dinv[s];
    // x rows are 14 floats = 56 bytes, always 8B-aligned -> float2 loads
    const float2* xr = (const float2*)(x + (size_t)s * IC);
    float* ar = aggx + (size_t)d * IC;
#pragma unroll
    for (int k = 0; k < IC / 2; ++k) {
        float2 v = xr[k];
        atomicAdd(&ar[2 * k + 0], v.x * w);
        atomicAdd(&ar[2 * k + 1], v.y * w);
    }
}

__global__ void k_node(const float* __restrict__ x, const float* __restrict__ dinv,
                       const float* __restrict__ aggx, const float* __restrict__ W1,
                       const float* __restrict__ b1, const float* __restrict__ W2,
                       const float* __restrict__ b2, float* __restrict__ h2b,
                       float* __restrict__ out) {
    __shared__ float sW1[IC * HC];
    __shared__ float sb1[HC];
    __shared__ float sW2[HC * OC];
    __shared__ float sb2[OC];
    int t = threadIdx.x;
    if (t < IC * HC) sW1[t] = W1[t];
    if (t < HC) sb1[t] = b1[t];
    if (t < HC * OC) sW2[t] = W2[t];
    if (t < OC) sb2[t] = b2[t];
    __syncthreads();

    int i = blockIdx.x * blockDim.x + t;
    if (i >= NN) return;

    float dv = dinv[i];
    float dv2 = dv * dv;
    float tt[IC];
#pragma unroll
    for (int c = 0; c < IC; ++c)
        tt[c] = dv * aggx[(size_t)i * IC + c] + dv2 * x[(size_t)i * IC + c];

    float r[HC];
#pragma unroll
    for (int f = 0; f < HC; ++f) {
        float acc = sb1[f];
#pragma unroll
        for (int c = 0; c < IC; ++c) acc = fmaf(tt[c], sW1[c * HC + f], acc);
        r[f] = fmaxf(acc, 0.0f);
    }

    float o0 = 0.0f, o1 = 0.0f;
#pragma unroll
    for (int f = 0; f < HC; ++f) {
        o0 = fmaf(r[f], sW2[f * OC + 0], o0);
        o1 = fmaf(r[f], sW2[f * OC + 1], o1);
    }
    h2b[(size_t)i * OC + 0] = o0;
    h2b[(size_t)i * OC + 1] = o1;
    out[(size_t)i * OC + 0] = o0 * dv2 + sb2[0];
    out[(size_t)i * OC + 1] = o1 * dv2 + sb2[1];
}

__global__ void k_scatter2(const void* __restrict__ ei, const int* __restrict__ flag,
                           const float* __restrict__ dinv, const float* __restrict__ h2b,
                           float* __restrict__ out) {
    int e = blockIdx.x * blockDim.x + threadIdx.x;
    if (e >= NE) return;
    int fl = *flag;
    int s, d;
    edge_ld(ei, fl, e, s, d);
    float nrm = dinv[s] * dinv[d];
    atomicAdd(&out[(size_t)d * OC + 0], h2b[(size_t)s * OC + 0] * nrm);
    atomicAdd(&out[(size_t)d * OC + 1], h2b[(size_t)s * OC + 1] * nrm);
}

extern "C" void kernel_launch(void* const* d_in, const int* in_sizes, int n_in,
                              void* d_out, int out_size, void* d_ws, size_t ws_size,
                              hipStream_t stream) {
    const float* x = (const float*)d_in[0];
    const void* ei = d_in[1];
    // d_in[2] = edge_attr (unused by GCNConv)
    const float* W1 = (const float*)d_in[3];
    const float* b1 = (const float*)d_in[4];
    const float* W2 = (const float*)d_in[5];
    const float* b2 = (const float*)d_in[6];
    float* out = (float*)d_out;

    float* deg = (float*)d_ws;                  // NN  (becomes dinv in-place)
    float* aggx = deg + NN;                     // NN*IC
    float* h2b = aggx + (size_t)NN * IC;        // NN*OC
    int* flag = (int*)(h2b + (size_t)NN * OC);  // 1

    const int B = 256;
    k_flag<<<1, 64, 0, stream>>>(ei, flag);
    k_init<<<(NN * IC + B - 1) / B, B, 0, stream>>>(deg, aggx);
    k_degree<<<(NE + B - 1) / B, B, 0, stream>>>(ei, flag, deg);
    k_dinv<<<(NN + B - 1) / B, B, 0, stream>>>(deg);
    k_scatter1<<<(NE + B - 1) / B, B, 0, stream>>>(ei, flag, x, deg, aggx);
    k_node<<<(NN + B - 1) / B, B, 0, stream>>>(x, deg, aggx, W1, b1, W2, b2, h2b, out);
    k_scatter2<<<(NE + B - 1) / B, B, 0, stream>>>(ei, flag, deg, h2b, out);
}

// Round 2
// 1170.064 us; speedup vs baseline: 4.7885x; 4.7885x over previous
//
#include <hip/hip_runtime.h>

// GCN 2-layer: N=200000 nodes, E=6400000 edges, 14 -> 16(relu) -> 2 channels.
// Round 2: replace float-atomic scatter (R1: 89.6M f32 atomics -> 2.8GB HBM
// write-through, 4.5ms) with CSR counting-sort + gather-side reduction.
//   1. count in-degree (int atomics), 2. exclusive scan -> row_start,
//   3. cursor scatter edges into csr_src (int atomics),
//   4. gather1: aggx[i] = sum_{s->i} dinv[s]*x[s]  (pure loads, 7x float2 lanes)
//   5. node MLP: out1=(dinv*aggx+dinv^2*x)@W1+b1, relu, h2b=@W2; out=self+b2
//   6. gather2: out[i] += dinv[i]*sum_{s->i} dinv[s]*h2b[s]  (2 lanes/node)
// edge_index dtype sniffed at runtime (int64 per reference vs int32).

constexpr int NN = 200000;
constexpr int NE = 6400000;
constexpr int IC = 14;
constexpr int HC = 16;
constexpr int OC = 2;
constexpr int NB = (NN + 255) / 256;  // 782 scan blocks

__global__ void k_flag(const void* __restrict__ ei, int* __restrict__ flag) {
    if (blockIdx.x == 0 && threadIdx.x == 0) {
        const unsigned long long* p = (const unsigned long long*)ei;
        unsigned long long acc = 0ULL;
        for (int i = 0; i < 64; ++i) acc |= (p[i] >> 32);
        *flag = (acc == 0ULL) ? 1 : 0;  // 1 => int64 indices, 0 => int32
    }
}

__global__ void k_zero(int* __restrict__ cnt) {
    int i = blockIdx.x * blockDim.x + threadIdx.x;
    if (i < NN) cnt[i] = 0;
}

__device__ __forceinline__ int edge_dst(const void* __restrict__ ei, int fl, int e) {
    if (fl) return (int)((const long long*)ei)[NE + e];
    return ((const int*)ei)[NE + e];
}

__device__ __forceinline__ void edge_ld(const void* __restrict__ ei, int fl, int e,
                                        int& s, int& d) {
    if (fl) {
        const long long* p = (const long long*)ei;
        s = (int)p[e];
        d = (int)p[NE + e];
    } else {
        const int* p = (const int*)ei;
        s = p[e];
        d = p[NE + e];
    }
}

__global__ void k_count(const void* __restrict__ ei, const int* __restrict__ flag,
                        int* __restrict__ cnt) {
    int e = blockIdx.x * blockDim.x + threadIdx.x;
    if (e >= NE) return;
    int d = edge_dst(ei, *flag, e);
    atomicAdd(&cnt[d], 1);
}

// Block-level inclusive scan of cnt -> row_start (temporarily inclusive), block sums -> bsum
__global__ void k_scan1(const int* __restrict__ cnt, int* __restrict__ incl,
                        int* __restrict__ bsum) {
    __shared__ int sh[256];
    int t = threadIdx.x;
    int i = blockIdx.x * 256 + t;
    int v = (i < NN) ? cnt[i] : 0;
    sh[t] = v;
    __syncthreads();
#pragma unroll
    for (int off = 1; off < 256; off <<= 1) {
        int add = (t >= off) ? sh[t - off] : 0;
        __syncthreads();
        sh[t] += add;
        __syncthreads();
    }
    if (i < NN) incl[i] = sh[t];
    if (t == 255) bsum[blockIdx.x] = sh[255];
}

// Exclusive scan of bsum in place (NB <= 1024)
__global__ void k_scan2(int* __restrict__ bsum) {
    __shared__ int sh[1024];
    int t = threadIdx.x;
    int v = (t < NB) ? bsum[t] : 0;
    sh[t] = v;
    __syncthreads();
#pragma unroll
    for (int off = 1; off < 1024; off <<= 1) {
        int add = (t >= off) ? sh[t - off] : 0;
        __syncthreads();
        sh[t] += add;
        __syncthreads();
    }
    if (t < NB) bsum[t] = sh[t] - v;
}

// Finalize: row_start exclusive, cursor init, dinv = rsqrt(deg+1)
__global__ void k_scan3(int* __restrict__ row_start, const int* __restrict__ cnt,
                        const int* __restrict__ bsum, int* __restrict__ cursor,
                        float* __restrict__ dinv) {
    int i = blockIdx.x * blockDim.x + threadIdx.x;
    if (i >= NN) return;
    int c = cnt[i];
    int rs = row_start[i] - c + bsum[i >> 8];
    row_start[i] = rs;
    cursor[i] = rs;
    dinv[i] = rsqrtf((float)c + 1.0f);
}

__global__ void k_fill(const void* __restrict__ ei, const int* __restrict__ flag,
                       int* __restrict__ cursor, int* __restrict__ csr_src) {
    int e = blockIdx.x * blockDim.x + threadIdx.x;
    if (e >= NE) return;
    int s, d;
    edge_ld(ei, *flag, e, s, d);
    int pos = atomicAdd(&cursor[d], 1);
    csr_src[pos] = s;
}

// 8 lanes per node; lanes 0..6 each own a float2 channel pair (14 ch)
__global__ void k_gather1(const int* __restrict__ row_start, const int* __restrict__ cursor,
                          const int* __restrict__ csr_src, const float* __restrict__ dinv,
                          const float* __restrict__ x, float* __restrict__ aggx) {
    int t = blockIdx.x * blockDim.x + threadIdx.x;
    int node = t >> 3;
    int lane = t & 7;
    if (node >= NN || lane >= 7) return;
    int beg = row_start[node];
    int end = cursor[node];  // == row_start + cnt after k_fill
    float ax = 0.0f, ay = 0.0f;
    for (int idx = beg; idx < end; ++idx) {
        int s = csr_src[idx];
        float w = dinv[s];
        float2 v = *(const float2*)(x + (size_t)s * IC + 2 * lane);
        ax = fmaf(v.x, w, ax);
        ay = fmaf(v.y, w, ay);
    }
    float2 r = {ax, ay};
    *(float2*)(aggx + (size_t)node * IC + 2 * lane) = r;
}

__global__ void k_node(const float* __restrict__ x, const float* __restrict__ dinv,
                       const float* __restrict__ aggx, const float* __restrict__ W1,
                       const float* __restrict__ b1, const float* __restrict__ W2,
                       const float* __restrict__ b2, float* __restrict__ h2b,
                       float* __restrict__ out) {
    __shared__ float sW1[IC * HC];
    __shared__ float sb1[HC];
    __shared__ float sW2[HC * OC];
    __shared__ float sb2[OC];
    int t = threadIdx.x;
    if (t < IC * HC) sW1[t] = W1[t];
    if (t < HC) sb1[t] = b1[t];
    if (t < HC * OC) sW2[t] = W2[t];
    if (t < OC) sb2[t] = b2[t];
    __syncthreads();

    int i = blockIdx.x * blockDim.x + t;
    if (i >= NN) return;

    float dv = dinv[i];
    float dv2 = dv * dv;
    float tt[IC];
#pragma unroll
    for (int c = 0; c < IC; ++c)
        tt[c] = dv * aggx[(size_t)i * IC + c] + dv2 * x[(size_t)i * IC + c];

    float r[HC];
#pragma unroll
    for (int f = 0; f < HC; ++f) {
        float acc = sb1[f];
#pragma unroll
        for (int c = 0; c < IC; ++c) acc = fmaf(tt[c], sW1[c * HC + f], acc);
        r[f] = fmaxf(acc, 0.0f);
    }

    float o0 = 0.0f, o1 = 0.0f;
#pragma unroll
    for (int f = 0; f < HC; ++f) {
        o0 = fmaf(r[f], sW2[f * OC + 0], o0);
        o1 = fmaf(r[f], sW2[f * OC + 1], o1);
    }
    h2b[(size_t)i * OC + 0] = o0;
    h2b[(size_t)i * OC + 1] = o1;
    out[(size_t)i * OC + 0] = o0 * dv2 + sb2[0];
    out[(size_t)i * OC + 1] = o1 * dv2 + sb2[1];
}

// 2 lanes per node, one output channel each
__global__ void k_gather2(const int* __restrict__ row_start, const int* __restrict__ cursor,
                          const int* __restrict__ csr_src, const float* __restrict__ dinv,
                          const float* __restrict__ h2b, float* __restrict__ out) {
    int t = blockIdx.x * blockDim.x + threadIdx.x;
    int node = t >> 1;
    int c = t & 1;
    if (node >= NN) return;
    int beg = row_start[node];
    int end = cursor[node];
    float acc = 0.0f;
    for (int idx = beg; idx < end; ++idx) {
        int s = csr_src[idx];
        acc = fmaf(dinv[s], h2b[(size_t)s * OC + c], acc);
    }
    out[(size_t)node * OC + c] += dinv[node] * acc;
}

extern "C" void kernel_launch(void* const* d_in, const int* in_sizes, int n_in,
                              void* d_out, int out_size, void* d_ws, size_t ws_size,
                              hipStream_t stream) {
    const float* x = (const float*)d_in[0];
    const void* ei = d_in[1];
    // d_in[2] = edge_attr (unused)
    const float* W1 = (const float*)d_in[3];
    const float* b1 = (const float*)d_in[4];
    const float* W2 = (const float*)d_in[5];
    const float* b2 = (const float*)d_in[6];
    float* out = (float*)d_out;

    int* cnt = (int*)d_ws;                     // NN
    int* row_start = cnt + NN;                 // NN
    int* cursor = row_start + NN;              // NN
    int* bsum = cursor + NN;                   // 1024
    int* flag = bsum + 1024;                   // 4 (padded)
    float* dinv = (float*)(flag + 4);          // NN
    float* aggx = dinv + NN;                   // NN*IC
    float* h2b = aggx + (size_t)NN * IC;       // NN*OC
    int* csr_src = (int*)(h2b + (size_t)NN * OC);  // NE

    const int B = 256;
    k_flag<<<1, 64, 0, stream>>>(ei, flag);
    k_zero<<<NB, B, 0, stream>>>(cnt);
    k_count<<<(NE + B - 1) / B, B, 0, stream>>>(ei, flag, cnt);
    k_scan1<<<NB, B, 0, stream>>>(cnt, row_start, bsum);
    k_scan2<<<1, 1024, 0, stream>>>(bsum);
    k_scan3<<<NB, B, 0, stream>>>(row_start, cnt, bsum, cursor, dinv);
    k_fill<<<(NE + B - 1) / B, B, 0, stream>>>(ei, flag, cursor, csr_src);
    k_gather1<<<(NN * 8 + B - 1) / B, B, 0, stream>>>(row_start, cursor, csr_src, dinv, x, aggx);
    k_node<<<NB, B, 0, stream>>>(x, dinv, aggx, W1, b1, W2, b2, h2b, out);
    k_gather2<<<(NN * 2 + B - 1) / B, B, 0, stream>>>(row_start, cursor, csr_src, dinv, h2b, out);
}

// Round 3
// 903.469 us; speedup vs baseline: 6.2015x; 1.2951x over previous
//
#include <hip/hip_runtime.h>

// GCN 2-layer: N=200000, E=6400000, 14 -> 16(relu) -> 2.
// Round 3: single-pass LDS-staged binning by dst>>10 (196 buckets x 1024 nodes),
// then per-bucket LDS-atomic aggregation for both layers. Eliminates the 12.8M
// global atomics + 392MB scattered-write amplification of the R2 CSR build.
//   k_binA: tile 6400 edges -> LDS hist -> scan -> rank/stage -> coalesced
//           segment writes of packed (dlow<<18|src) u32; 196 global atomics/tile.
//   k_b1:   per-bucket degree count in LDS -> gcnt
//   k_b2:   per-bucket sum dinv[src]*x[src] (14ch) via ds_add_f32, stride-15 pad
//   k_node: out1=(dinv*aggx+dinv^2*x)@W1+b1, relu, h2b=@W2, out=self+b2
//   k_b3:   per-bucket sum dinv[src]*h2b[src] (2ch), out += dinv[dst]*acc
// Fixed bucket capacity = mean+12sigma; overflow edges go to a list handled by
// tiny fixup kernels (no-ops in practice, correctness preserved).

constexpr int NN = 200000;
constexpr int NE = 6400000;
constexpr int IC = 14;
constexpr int HC = 16;
constexpr int OC = 2;

constexpr int NBUCK = (NN + 1023) >> 10;   // 196 buckets of 1024 nodes
constexpr int CAP = 34816;                 // per-bucket capacity (mean 32653 + 12 sigma)
constexpr int TILE = 6400;                 // edges per binA block (NE = 6400*1000 exactly)
constexpr int IPT = TILE / 256;            // 25 items per thread
constexpr int NTILE = NE / TILE;           // 1000
constexpr int OVFCAP = 65536;
constexpr int NB = (NN + 255) / 256;       // 782

typedef unsigned long long ull;

__global__ void k_flag(const void* __restrict__ ei, int* __restrict__ flag) {
    if (blockIdx.x == 0 && threadIdx.x == 0) {
        const ull* p = (const ull*)ei;
        ull acc = 0ULL;
        for (int i = 0; i < 64; ++i) acc |= (p[i] >> 32);
        *flag = (acc == 0ULL) ? 1 : 0;  // 1 => int64 indices, 0 => int32
    }
}

__global__ void k_init(int* __restrict__ gcur) {
    int t = threadIdx.x;
    if (t < NBUCK) gcur[t] = t * CAP;
    if (t == NBUCK) gcur[t] = 0;  // overflow counter
}

__device__ __forceinline__ int edge_src(const void* __restrict__ ei, int fl, int e) {
    if (fl) return (int)((const long long*)ei)[e];
    return ((const int*)ei)[e];
}
__device__ __forceinline__ int edge_dst(const void* __restrict__ ei, int fl, int e) {
    if (fl) return (int)((const long long*)ei)[NE + e];
    return ((const int*)ei)[NE + e];
}

__global__ __launch_bounds__(256) void k_binA(const void* __restrict__ ei,
                                              const int* __restrict__ flag,
                                              int* __restrict__ gcur,
                                              unsigned* __restrict__ binned,
                                              ull* __restrict__ ovf) {
    __shared__ int hist[NBUCK];     // counts, then staging cursors
    __shared__ int lofs[NBUCK];     // local exclusive offsets
    __shared__ int gofs[NBUCK];     // reserved global offsets
    __shared__ int scanbuf[256];
    __shared__ unsigned stage[TILE];
    __shared__ unsigned char sb[TILE];

    int t = threadIdx.x;
    int fl = *flag;
    int tile0 = blockIdx.x * TILE;

    if (t < NBUCK) hist[t] = 0;
    __syncthreads();

    int dsts[IPT];
#pragma unroll
    for (int k = 0; k < IPT; ++k) {
        int e = tile0 + k * 256 + t;
        int d = edge_dst(ei, fl, e);
        dsts[k] = d;
        atomicAdd(&hist[d >> 10], 1);
    }
    __syncthreads();

    // block exclusive scan over NBUCK counts + global reservation
    int c = (t < NBUCK) ? hist[t] : 0;
    scanbuf[t] = c;
    __syncthreads();
#pragma unroll
    for (int off = 1; off < 256; off <<= 1) {
        int v = (t >= off) ? scanbuf[t - off] : 0;
        __syncthreads();
        scanbuf[t] += v;
        __syncthreads();
    }
    if (t < NBUCK) {
        int excl = scanbuf[t] - c;
        lofs[t] = excl;
        hist[t] = excl;                       // becomes staging cursor
        gofs[t] = atomicAdd(&gcur[t], c);     // reserve segment space
    }
    __syncthreads();

    // rank + stage (random LDS writes, cheap)
#pragma unroll
    for (int k = 0; k < IPT; ++k) {
        int e = tile0 + k * 256 + t;
        int s = edge_src(ei, fl, e);
        int d = dsts[k];
        int b = d >> 10;
        int pos = atomicAdd(&hist[b], 1);
        stage[pos] = (unsigned)(((d & 1023) << 18) | s);
        sb[pos] = (unsigned char)b;
    }
    __syncthreads();

    // coalesced write-out: consecutive i within a bucket -> consecutive dest
    for (int i = t; i < TILE; i += 256) {
        int b = sb[i];
        unsigned pack = stage[i];
        int dest = gofs[b] + (i - lofs[b]);
        if (dest < (b + 1) * CAP) {
            binned[dest] = pack;
        } else {  // overflow (never in practice): save full (dst,src)
            int op = atomicAdd(&gcur[NBUCK], 1);
            if (op < OVFCAP) {
                int d = (b << 10) | (int)(pack >> 18);
                int s = (int)(pack & 0x3FFFF);
                ovf[op] = ((ull)d << 32) | (unsigned)s;
            }
        }
    }
}

__global__ __launch_bounds__(256) void k_b1(const int* __restrict__ gcur,
                                            const unsigned* __restrict__ binned,
                                            int* __restrict__ gcnt) {
    __shared__ int cnt[1024];
    int b = blockIdx.x;
    int t = threadIdx.x;
    for (int i = t; i < 1024; i += 256) cnt[i] = 0;
    __syncthreads();
    int base = b * CAP;
    int n = min(gcur[b], (b + 1) * CAP) - base;
    for (int i = t; i < n; i += 256) {
        unsigned pack = binned[base + i];
        atomicAdd(&cnt[pack >> 18], 1);
    }
    __syncthreads();
    for (int i = t; i < 1024; i += 256) {
        int g = (b << 10) + i;
        if (g < NN) gcnt[g] = cnt[i];
    }
}

__global__ void k_ovf1(const int* __restrict__ gcur, const ull* __restrict__ ovf,
                       int* __restrict__ gcnt) {
    int nov = min(gcur[NBUCK], OVFCAP);
    for (int i = blockIdx.x * blockDim.x + threadIdx.x; i < nov; i += gridDim.x * blockDim.x) {
        int d = (int)(ovf[i] >> 32);
        atomicAdd(&gcnt[d], 1);
    }
}

__global__ void k_dinv(const int* __restrict__ gcnt, float* __restrict__ dinv) {
    int i = blockIdx.x * blockDim.x + threadIdx.x;
    if (i < NN) dinv[i] = rsqrtf((float)gcnt[i] + 1.0f);
}

__global__ __launch_bounds__(256) void k_b2(const int* __restrict__ gcur,
                                            const unsigned* __restrict__ binned,
                                            const float* __restrict__ dinv,
                                            const float* __restrict__ x,
                                            float* __restrict__ aggx) {
    __shared__ float acc[1024 * 15];  // stride 15: gcd(15,32)=1, no bank clustering
    int b = blockIdx.x;
    int t = threadIdx.x;
    for (int i = t; i < 1024 * 15; i += 256) acc[i] = 0.0f;
    __syncthreads();
    int base = b * CAP;
    int n = min(gcur[b], (b + 1) * CAP) - base;
    for (int i = t; i < n; i += 256) {
        unsigned pack = binned[base + i];
        int s = (int)(pack & 0x3FFFF);
        int dl = (int)(pack >> 18);
        float w = dinv[s];
        const float2* xr = (const float2*)(x + (size_t)s * IC);
        float* a = &acc[dl * 15];
#pragma unroll
        for (int k = 0; k < IC / 2; ++k) {
            float2 v = xr[k];
            atomicAdd(&a[2 * k + 0], v.x * w);
            atomicAdd(&a[2 * k + 1], v.y * w);
        }
    }
    __syncthreads();
    int nloc = min(1024, NN - (b << 10));
    for (int nn = t; nn < nloc; nn += 256) {
        int g = (b << 10) + nn;
        float2* dst = (float2*)(aggx + (size_t)g * IC);
#pragma unroll
        for (int k = 0; k < IC / 2; ++k) {
            float2 v = {acc[nn * 15 + 2 * k], acc[nn * 15 + 2 * k + 1]};
            dst[k] = v;
        }
    }
}

__global__ void k_ovf2(const int* __restrict__ gcur, const ull* __restrict__ ovf,
                       const float* __restrict__ dinv, const float* __restrict__ x,
                       float* __restrict__ aggx) {
    int nov = min(gcur[NBUCK], OVFCAP);
    for (int i = blockIdx.x * blockDim.x + threadIdx.x; i < nov; i += gridDim.x * blockDim.x) {
        int d = (int)(ovf[i] >> 32);
        int s = (int)(ovf[i] & 0xFFFFFFFFu);
        float w = dinv[s];
        for (int c = 0; c < IC; ++c)
            atomicAdd(&aggx[(size_t)d * IC + c], w * x[(size_t)s * IC + c]);
    }
}

__global__ void k_node(const float* __restrict__ x, const float* __restrict__ dinv,
                       const float* __restrict__ aggx, const float* __restrict__ W1,
                       const float* __restrict__ b1, const float* __restrict__ W2,
                       const float* __restrict__ b2, float* __restrict__ h2b,
                       float* __restrict__ out) {
    __shared__ float sW1[IC * HC];
    __shared__ float sb1[HC];
    __shared__ float sW2[HC * OC];
    __shared__ float sb2[OC];
    int t = threadIdx.x;
    if (t < IC * HC) sW1[t] = W1[t];
    if (t < HC) sb1[t] = b1[t];
    if (t < HC * OC) sW2[t] = W2[t];
    if (t < OC) sb2[t] = b2[t];
    __syncthreads();

    int i = blockIdx.x * blockDim.x + t;
    if (i >= NN) return;

    float dv = dinv[i];
    float dv2 = dv * dv;
    float tt[IC];
#pragma unroll
    for (int c = 0; c < IC; ++c)
        tt[c] = dv * aggx[(size_t)i * IC + c] + dv2 * x[(size_t)i * IC + c];

    float r[HC];
#pragma unroll
    for (int f = 0; f < HC; ++f) {
        float acc = sb1[f];
#pragma unroll
        for (int c = 0; c < IC; ++c) acc = fmaf(tt[c], sW1[c * HC + f], acc);
        r[f] = fmaxf(acc, 0.0f);
    }

    float o0 = 0.0f, o1 = 0.0f;
#pragma unroll
    for (int f = 0; f < HC; ++f) {
        o0 = fmaf(r[f], sW2[f * OC + 0], o0);
        o1 = fmaf(r[f], sW2[f * OC + 1], o1);
    }
    h2b[(size_t)i * OC + 0] = o0;
    h2b[(size_t)i * OC + 1] = o1;
    out[(size_t)i * OC + 0] = o0 * dv2 + sb2[0];
    out[(size_t)i * OC + 1] = o1 * dv2 + sb2[1];
}

__global__ __launch_bounds__(256) void k_b3(const int* __restrict__ gcur,
                                            const unsigned* __restrict__ binned,
                                            const float* __restrict__ dinv,
                                            const float* __restrict__ h2b,
                                            float* __restrict__ out) {
    __shared__ float acc2[1024 * 3];  // stride 3: gcd(3,32)=1
    int b = blockIdx.x;
    int t = threadIdx.x;
    for (int i = t; i < 1024 * 3; i += 256) acc2[i] = 0.0f;
    __syncthreads();
    int base = b * CAP;
    int n = min(gcur[b], (b + 1) * CAP) - base;
    for (int i = t; i < n; i += 256) {
        unsigned pack = binned[base + i];
        int s = (int)(pack & 0x3FFFF);
        int dl = (int)(pack >> 18);
        float w = dinv[s];
        float2 h = *(const float2*)(h2b + (size_t)s * OC);
        atomicAdd(&acc2[dl * 3 + 0], w * h.x);
        atomicAdd(&acc2[dl * 3 + 1], w * h.y);
    }
    __syncthreads();
    int nloc = min(1024, NN - (b << 10));
    for (int nn = t; nn < nloc; nn += 256) {
        int g = (b << 10) + nn;
        float dv = dinv[g];
        out[(size_t)g * OC + 0] += dv * acc2[nn * 3 + 0];
        out[(size_t)g * OC + 1] += dv * acc2[nn * 3 + 1];
    }
}

__global__ void k_ovf3(const int* __restrict__ gcur, const ull* __restrict__ ovf,
                       const float* __restrict__ dinv, const float* __restrict__ h2b,
                       float* __restrict__ out) {
    int nov = min(gcur[NBUCK], OVFCAP);
    for (int i = blockIdx.x * blockDim.x + threadIdx.x; i < nov; i += gridDim.x * blockDim.x) {
        int d = (int)(ovf[i] >> 32);
        int s = (int)(ovf[i] & 0xFFFFFFFFu);
        float nrm = dinv[s] * dinv[d];
        atomicAdd(&out[(size_t)d * OC + 0], nrm * h2b[(size_t)s * OC + 0]);
        atomicAdd(&out[(size_t)d * OC + 1], nrm * h2b[(size_t)s * OC + 1]);
    }
}

extern "C" void kernel_launch(void* const* d_in, const int* in_sizes, int n_in,
                              void* d_out, int out_size, void* d_ws, size_t ws_size,
                              hipStream_t stream) {
    const float* x = (const float*)d_in[0];
    const void* ei = d_in[1];
    // d_in[2] = edge_attr (unused)
    const float* W1 = (const float*)d_in[3];
    const float* b1 = (const float*)d_in[4];
    const float* W2 = (const float*)d_in[5];
    const float* b2 = (const float*)d_in[6];
    float* out = (float*)d_out;

    ull* ovf = (ull*)d_ws;                          // OVFCAP (8B aligned first)
    int* gcur = (int*)(ovf + OVFCAP);               // NBUCK+1 -> pad 256
    int* flag = gcur + 256;                         // 4
    int* gcnt = flag + 4;                           // NN
    float* dinv = (float*)(gcnt + NN);              // NN
    float* aggx = dinv + NN;                        // NN*IC
    float* h2b = aggx + (size_t)NN * IC;            // NN*OC
    unsigned* binned = (unsigned*)(h2b + (size_t)NN * OC);  // NBUCK*CAP

    k_flag<<<1, 64, 0, stream>>>(ei, flag);
    k_init<<<1, 256, 0, stream>>>(gcur);
    k_binA<<<NTILE, 256, 0, stream>>>(ei, flag, gcur, binned, ovf);
    k_b1<<<NBUCK, 256, 0, stream>>>(gcur, binned, gcnt);
    k_ovf1<<<8, 256, 0, stream>>>(gcur, ovf, gcnt);
    k_dinv<<<NB, 256, 0, stream>>>(gcnt, dinv);
    k_b2<<<NBUCK, 256, 0, stream>>>(gcur, binned, dinv, x, aggx);
    k_ovf2<<<8, 256, 0, stream>>>(gcur, ovf, dinv, x, aggx);
    k_node<<<NB, 256, 0, stream>>>(x, dinv, aggx, W1, b1, W2, b2, h2b, out);
    k_b3<<<NBUCK, 256, 0, stream>>>(gcur, binned, dinv, h2b, out);
    k_ovf3<<<8, 256, 0, stream>>>(gcur, ovf, dinv, h2b, out);
}